// Round 6
// baseline (227.901 us; speedup 1.0000x reference)
//
#include <hip/hip_runtime.h>
#include <math.h>

typedef __attribute__((ext_vector_type(8))) short short8;
typedef __attribute__((ext_vector_type(4))) float floatx4;

__device__ __forceinline__ void load_lds16(const void* g, void* l) {
    __builtin_amdgcn_global_load_lds((const __attribute__((address_space(1))) void*)g,
                                     (__attribute__((address_space(3))) void*)l,
                                     16, 0, 0);
}

__device__ __forceinline__ unsigned short f2bf(float x) {
    union { float f; unsigned int u; } v; v.f = x;
    unsigned int r = v.u + 0x7fffu + ((v.u >> 16) & 1u);
    return (unsigned short)(r >> 16);
}

// pack two fp32 -> two bf16 (round-half-up) in one v_perm_b32
__device__ __forceinline__ unsigned int pack_bf(float f0, float f1) {
    union { float f; unsigned int u; } a, b;
    a.f = f0; b.f = f1;
    return __builtin_amdgcn_perm(b.u + 0x8000u, a.u + 0x8000u, 0x07060302u);
}

__device__ __forceinline__ float fast_exp2(float x) {
#if __has_builtin(__builtin_amdgcn_exp2f)
    return __builtin_amdgcn_exp2f(x);
#else
    return __expf(x * 0.69314718056f);
#endif
}

__device__ __forceinline__ float fast_rcp(float x) {
#if __has_builtin(__builtin_amdgcn_rcpf)
    return __builtin_amdgcn_rcpf(x);
#else
    return 1.0f / x;
#endif
}

#define NEG_LOG2E (-1.4426950408889634f)

// ---- prep: weights -> bf16 in MFMA-fragment order + Toeplitz XW build ----
// blocks: [0,512) w0 | [512,6656) w | [6656,7680) wf-pad | [7680,11776) XW rows
__global__ void prep(const float* __restrict__ w0, const float* __restrict__ w,
                     const float* __restrict__ wf, const float* __restrict__ xi,
                     unsigned short* __restrict__ w0d, unsigned short* __restrict__ wd,
                     unsigned short* __restrict__ wfd, unsigned int* __restrict__ xw) {
    const int bid = blockIdx.x;
    if (bid < 6656) {
        const bool is0 = bid < 512;
        const int c = (is0 ? bid : bid - 512) * 256 + threadIdx.x;
        const int cpm = is0 ? 2048 : 8192;
        const int Kk  = is0 ? 2 : 8;
        const int K   = Kk * 32;
        const int mm  = c / cpm;
        const int cm  = c - mm * cpm;
        const int rblk = cm / (Kk * 64);
        const int rem  = cm - rblk * (Kk * 64);
        const int kk   = rem >> 6;
        const int lane = rem & 63;
        const int r  = rblk * 16 + (lane & 15);
        const int k0 = kk * 32 + (lane >> 4) * 8;
        const float* srcp = (is0 ? w0 : w) + ((size_t)mm * 256 + r) * K + k0;
        unsigned short* dstp = (is0 ? w0d : wd) + (size_t)c * 8;
        float4 a = *(const float4*)srcp;
        float4 b = *(const float4*)(srcp + 4);
        short8 o = { (short)f2bf(a.x), (short)f2bf(a.y), (short)f2bf(a.z), (short)f2bf(a.w),
                     (short)f2bf(b.x), (short)f2bf(b.y), (short)f2bf(b.z), (short)f2bf(b.w) };
        *(short8*)dstp = o;
    } else if (bid < 7680) {
        const int c = (bid - 6656) * 256 + threadIdx.x;
        const int m  = c >> 12;
        const int cm = c & 4095;
        const int rblk = cm >> 9;
        const int rem  = cm & 511;
        const int kk   = rem >> 6;
        const int lane = rem & 63;
        const int r  = rblk * 16 + (lane & 15);
        const int k0 = kk * 32 + (lane >> 4) * 8;
        short8 o = {0,0,0,0,0,0,0,0};
        if (r < 65) {
            const float* srcp = wf + ((size_t)m * 65 + r) * 256 + k0;
            float4 a = *(const float4*)srcp;
            float4 b = *(const float4*)(srcp + 4);
            o = (short8){ (short)f2bf(a.x), (short)f2bf(a.y), (short)f2bf(a.z), (short)f2bf(a.w),
                          (short)f2bf(b.x), (short)f2bf(b.y), (short)f2bf(b.z), (short)f2bf(b.w) };
        }
        *(short8*)(wfd + (size_t)c * 8) = o;
    } else {
        const int n = bid - 7680;
        #pragma unroll
        for (int t = 0; t < 9; ++t) {
            const int idx = t * 256 + threadIdx.x;
            if (idx < 2176) {
                const int m = idx / 34;
                const int pos = idx - m * 34;
                const int j0 = pos * 2;
                const float* xim = xi + (size_t)m * 4160 + n;
                const float v0 = (j0 < 65) ? xim[j0] : 0.0f;
                const float v1 = (j0 + 1 < 65) ? xim[j0 + 1] : 0.0f;
                xw[(size_t)n * 2176 + idx] =
                    (unsigned int)f2bf(v0) | ((unsigned int)f2bf(v1) << 16);
            }
        }
    }
}

// ---- weight fragments -> registers, once per layer (amortized over 2 sub-tiles) ----
template<int K, int I>
__device__ __forceinline__ void load_w(
    const unsigned short* __restrict__ Wt, int wave, int lane, short8 (&w)[I][K / 32])
{
    constexpr int Kk = K / 32;
    const unsigned short* wb = Wt + ((size_t)(wave * I * Kk) * 64 + lane) * 8;
    #pragma unroll
    for (int i = 0; i < I; ++i)
        #pragma unroll
        for (int kk = 0; kk < Kk; ++kk)
            w[i][kk] = *(const short8*)(wb + (size_t)(i * Kk + kk) * 512);
}

// ---- MFMA sweep over one 64-col sub-tile t, weights from registers ----
// X layout: X[b][k] at b*K + ((k/8) ^ (b&7))*8 + (k&7)   (shorts)
template<int K, int I>
__device__ __forceinline__ void mfma_tile(
    const short8 (&w)[I][K / 32], const unsigned short* src, int t,
    int quad, int l16, floatx4 (&acc)[I][4])
{
    constexpr int Kk = K / 32;
    #pragma unroll
    for (int i = 0; i < I; ++i)
        #pragma unroll
        for (int j = 0; j < 4; ++j) acc[i][j] = (floatx4){0.f, 0.f, 0.f, 0.f};
    #pragma unroll
    for (int kk = 0; kk < Kk; ++kk) {
        short8 bf[4];
        #pragma unroll
        for (int j = 0; j < 4; ++j) {
            const int cb = t * 64 + j * 16 + l16;
            bf[j] = *(const short8*)&src[cb * K + (((kk * 4 + quad) ^ (cb & 7)) * 8)];
        }
        #pragma unroll
        for (int i = 0; i < I; ++i)
            #pragma unroll
            for (int j = 0; j < 4; ++j)
                acc[i][j] = __builtin_amdgcn_mfma_f32_16x16x32_bf16(w[i][kk], bf[j], acc[i][j], 0, 0, 0);
    }
}

// epilogue for sub-tile t: fused bias+sigmoid, perm pack, in-place K_out=256 layout
template<int I>
__device__ __forceinline__ void mlp_write_t(
    const float* __restrict__ bm, unsigned short* dst, int t,
    int wave, int quad, int l16, floatx4 (&acc)[I][4])
{
    const int rbw = wave * (I * 16);
    #pragma unroll
    for (int i = 0; i < I; ++i) {
        const int rb = rbw + i * 16 + quad * 4;
        float c0 = bm[rb]     * NEG_LOG2E;
        float c1 = bm[rb + 1] * NEG_LOG2E;
        float c2 = bm[rb + 2] * NEG_LOG2E;
        float c3 = bm[rb + 3] * NEG_LOG2E;
        #pragma unroll
        for (int j = 0; j < 4; ++j) {
            const int cb = t * 64 + j * 16 + l16;
            float r0 = fast_rcp(1.0f + fast_exp2(fmaf(acc[i][j][0], NEG_LOG2E, c0)));
            float r1 = fast_rcp(1.0f + fast_exp2(fmaf(acc[i][j][1], NEG_LOG2E, c1)));
            float r2 = fast_rcp(1.0f + fast_exp2(fmaf(acc[i][j][2], NEG_LOG2E, c2)));
            float r3 = fast_rcp(1.0f + fast_exp2(fmaf(acc[i][j][3], NEG_LOG2E, c3)));
            uint2 o = { pack_bf(r0, r1), pack_bf(r2, r3) };
            *(uint2*)&dst[cb * 256 + (((rb >> 3) ^ (cb & 7)) * 8) + (rb & 7)] = o;
        }
    }
}

// ---- fused MLP, weight-register-resident, 8-wave blocks (R6) ----
// grid 512 = 64 m x 8 batch-tiles of 128; 512 thr (8 waves, I=2); 2 blocks/CU
// -> 16 waves/CU = 4 waves/SIMD (R5 had 2/SIMD: pipes serialized, sum of
// MFMA 15.5 + LDS 13 + VALU 16 us == measured 49.8). Doubled TLP lets
// independent waves overlap MFMA/VALU/LDS phases. Weight stream, MFMA:load
// ratio (8:1) and per-element math identical to R5 -> absmax unchanged.
// VGPR budget: w[2][8]=64 + acc[2][4]=32 + bf/addr ~= 128 (cap at (512,4)).
__global__ __launch_bounds__(512, 4)
void fused_mlp(const float* __restrict__ u,
               const unsigned short* __restrict__ w0_bf, const float* __restrict__ b0_,
               const unsigned short* __restrict__ w_bf,  const float* __restrict__ b_,
               const unsigned short* __restrict__ wf_bf, const float* __restrict__ bf_,
               unsigned short* __restrict__ Gflat) {
    __shared__ unsigned short X[128 * 256];   // 64 KB

    const int bid = blockIdx.x;
    const int xcd = bid & 7, slot = bid >> 3;           // slot 0..63
    const int m  = (xcd << 3) + (slot >> 3);            // 8 m per XCD
    const int b0 = (slot & 7) << 7;                     // 8 batch-tiles of 128
    const int tid = threadIdx.x, wave = tid >> 6, lane = tid & 63;
    const int quad = lane >> 4, l16 = lane & 15;

    // stage u (fp32) -> X (bf16, K=64 layout), perm-packed: 128 b x 4 thr each
    {
        const int b = tid >> 2, dc = tid & 3;
        const float* up = u + (size_t)(b0 + b) * 64 + dc * 16;
        float4 v0 = *(const float4*)(up);
        float4 v1 = *(const float4*)(up + 4);
        float4 v2 = *(const float4*)(up + 8);
        float4 v3 = *(const float4*)(up + 12);
        uint4 p0 = { pack_bf(v0.x, v0.y), pack_bf(v0.z, v0.w),
                     pack_bf(v1.x, v1.y), pack_bf(v1.z, v1.w) };
        uint4 p1 = { pack_bf(v2.x, v2.y), pack_bf(v2.z, v2.w),
                     pack_bf(v3.x, v3.y), pack_bf(v3.z, v3.w) };
        *(uint4*)&X[b * 64 + (((dc * 2)     ^ (b & 7)) * 8)] = p0;
        *(uint4*)&X[b * 64 + (((dc * 2 + 1) ^ (b & 7)) * 8)] = p1;
    }
    __syncthreads();

    floatx4 acc[2][4];

    // ---- layer 0 (K=64): both sub-tiles computed before any write ----
    // (64-layout [0,16KB) overlaps 256-layout -> no partial overwrite allowed)
    {
        short8 w0r[2][2];
        load_w<64, 2>(w0_bf + (size_t)m * 16384, wave, lane, w0r);
        floatx4 acc2[2][4];
        mfma_tile<64, 2>(w0r, X, 0, quad, l16, acc);
        mfma_tile<64, 2>(w0r, X, 1, quad, l16, acc2);
        __syncthreads();
        mlp_write_t<2>(b0_ + (size_t)m * 256, X, 0, wave, quad, l16, acc);
        mlp_write_t<2>(b0_ + (size_t)m * 256, X, 1, wave, quad, l16, acc2);
        __syncthreads();
    }

    // ---- main layers (K=256): weights in regs, 2 sub-tiles, 2 barriers/layer ----
    #pragma unroll 1
    for (int l = 0; l < 3; ++l) {
        short8 wr[2][8];
        load_w<256, 2>(w_bf + ((size_t)l * 64 + m) * 65536, wave, lane, wr);
        const float* bm = b_ + ((size_t)l * 64 + m) * 256;
        mfma_tile<256, 2>(wr, X, 0, quad, l16, acc);
        __syncthreads();
        mlp_write_t<2>(bm, X, 0, wave, quad, l16, acc);   // writes b 0-63
        mfma_tile<256, 2>(wr, X, 1, quad, l16, acc);      // reads  b 64-127 (disjoint)
        __syncthreads();
        mlp_write_t<2>(bm, X, 1, wave, quad, l16, acc);
    }
    __syncthreads();   // all write1 visible before final layer reads tile 1

    // ---- final layer (K=256): waves 0-4, I=1 (80 rows >= 68), direct G write ----
    if (wave < 5) {
        short8 wfr[1][8];
        load_w<256, 1>(wf_bf + (size_t)m * 32768, wave, lane, wfr);
        const float* bm = bf_ + (size_t)m * 65;
        unsigned short* Gg = Gflat + (size_t)b0 * 4352 + m * 68;
        floatx4 acf[1][4];
        #pragma unroll
        for (int t = 0; t < 2; ++t) {
            mfma_tile<256, 1>(wfr, X, t, quad, l16, acf);
            const int rb = wave * 16 + quad * 4;
            if (rb < 68) {
                float c[4];
                #pragma unroll
                for (int rr = 0; rr < 4; ++rr)
                    c[rr] = (rb + rr < 65) ? bm[rb + rr] * NEG_LOG2E : 0.0f;
                #pragma unroll
                for (int j = 0; j < 4; ++j) {
                    const int cb = t * 64 + j * 16 + l16;
                    float r0 = fast_rcp(1.0f + fast_exp2(fmaf(acf[0][j][0], NEG_LOG2E, c[0])));
                    float r1 = fast_rcp(1.0f + fast_exp2(fmaf(acf[0][j][1], NEG_LOG2E, c[1])));
                    float r2 = fast_rcp(1.0f + fast_exp2(fmaf(acf[0][j][2], NEG_LOG2E, c[2])));
                    float r3 = fast_rcp(1.0f + fast_exp2(fmaf(acf[0][j][3], NEG_LOG2E, c[3])));
                    uint2 o = { pack_bf(r0, r1), pack_bf(r2, r3) };
                    *(uint2*)&Gg[(size_t)cb * 4352 + rb] = o;
                }
            }
        }
    }
}

// ---- contraction: P[kc][n][b] partials; K=4352, K-split x4, 256 thr, 128x128 ----
// (256,4): 1024 blocks / 256 CU = exactly 4 blocks/CU; at (256,3) the grid ran
// as 768 + 256-block tail at 1/3 occupancy. LDS 32KB x 4 = 128KB fits.
__global__ __launch_bounds__(256, 4)
void contract_gemm(const unsigned short* __restrict__ XW,
                   const unsigned short* __restrict__ G,
                   float* __restrict__ P) {
    const int bid = blockIdx.x;
    const int xcd = bid & 7, slot = bid >> 3;          // 0..127
    const int kc  = slot >> 5;                          // 0..3
    const int rst = slot & 31;
    const int r0 = ((xcd << 2) + (rst >> 3)) << 7;      // n-tile (XCD-colocated)
    const int c0 = (rst & 7) << 7;                      // b-tile
    const int kb = kc * 1088;
    float* Pc = P + (size_t)kc * 4096 * 1024;

    __shared__ unsigned short As[128 * 64];
    __shared__ unsigned short Bs[128 * 64];

    const int tid = threadIdx.x;
    const int wave = tid >> 6, lane = tid & 63;
    const int quad = lane >> 4, l16 = lane & 15;
    const int wr = (wave & 1) * 64;
    const int wc = (wave >> 1) * 64;
    const int srow = wave * 32 + (lane >> 3);
    const int spos = lane & 7;

    floatx4 acc[4][4];
    const floatx4 zero = {0.f, 0.f, 0.f, 0.f};
    #pragma unroll
    for (int i = 0; i < 4; ++i)
        #pragma unroll
        for (int j = 0; j < 4; ++j) acc[i][j] = zero;

    for (int k0 = kb; k0 < kb + 1088; k0 += 64) {
        #pragma unroll
        for (int t = 0; t < 4; ++t) {
            const int row = srow + t * 8;
            const int fc  = spos ^ (row & 7);
            load_lds16(XW + (size_t)(r0 + row) * 4352 + k0 + fc * 8,
                       &As[(wave * 32 + t * 8) * 64]);
            load_lds16(G + (size_t)(c0 + row) * 4352 + k0 + fc * 8,
                       &Bs[(wave * 32 + t * 8) * 64]);
        }
        __syncthreads();

        #pragma unroll
        for (int kk = 0; kk < 2; ++kk) {
            short8 af[4], bfr[4];
            #pragma unroll
            for (int i = 0; i < 4; ++i) {
                const int ra = wr + i * 16 + l16;
                af[i]  = *(const short8*)&As[ra * 64 + (((kk * 4 + quad) ^ (ra & 7)) * 8)];
                const int cb = wc + i * 16 + l16;
                bfr[i] = *(const short8*)&Bs[cb * 64 + (((kk * 4 + quad) ^ (cb & 7)) * 8)];
            }
            #pragma unroll
            for (int i = 0; i < 4; ++i)
                #pragma unroll
                for (int j = 0; j < 4; ++j)
                    acc[i][j] = __builtin_amdgcn_mfma_f32_16x16x32_bf16(af[i], bfr[j], acc[i][j], 0, 0, 0);
        }
        __syncthreads();
    }

    #pragma unroll
    for (int i = 0; i < 4; ++i) {
        const int rb = r0 + wr + i * 16 + quad * 4;
        #pragma unroll
        for (int rr = 0; rr < 4; ++rr)
            #pragma unroll
            for (int j = 0; j < 4; ++j) {
                const int col = c0 + wc + j * 16 + l16;
                Pc[(size_t)(rb + rr) * 1024 + col] = acc[i][j][rr];
            }
    }
}

// ---- final reduce of 4 K-partials ----
__global__ void reduce4(const float* __restrict__ P, float* __restrict__ out) {
    const int i = blockIdx.x * 256 + threadIdx.x;
    const float4* p = (const float4*)P;
    float4 a = p[i], b = p[i + 1048576], c = p[i + 2097152], d = p[i + 3145728];
    ((float4*)out)[i] = (float4){ a.x + b.x + c.x + d.x, a.y + b.y + c.y + d.y,
                                  a.z + b.z + c.z + d.z, a.w + b.w + c.w + d.w };
}

extern "C" void kernel_launch(void* const* d_in, const int* in_sizes, int n_in,
                              void* d_out, int out_size, void* d_ws, size_t ws_size,
                              hipStream_t stream) {
    const float* u   = (const float*)d_in[0];
    const float* w0  = (const float*)d_in[1];
    const float* b0_ = (const float*)d_in[2];
    const float* w   = (const float*)d_in[3];
    const float* b   = (const float*)d_in[4];
    const float* wf  = (const float*)d_in[5];
    const float* bf_ = (const float*)d_in[6];
    const float* xi  = (const float*)d_in[7];
    float* out = (float*)d_out;

    unsigned short* w0_bf = (unsigned short*)d_ws;             // 1,048,576
    unsigned short* w_bf  = w0_bf + 1048576;                   // 12,582,912
    unsigned short* wf_bf = w_bf  + 12582912;                  // 2,097,152
    unsigned short* Gflat = wf_bf + 2097152;                   // 4,456,448 (1024 x 4352)
    unsigned short* XW    = Gflat + 4456448;                   // 17,825,792 (4096 x 4352)
    float*          P     = (float*)(XW + 17825792);           // 4 x 4096 x 1024 fp32

    prep<<<11776, 256, 0, stream>>>(w0, w, wf, xi, w0_bf, w_bf, wf_bf, (unsigned int*)XW);
    fused_mlp<<<512, 512, 0, stream>>>(u, w0_bf, b0_, w_bf, b, wf_bf, bf_, Gflat);
    contract_gemm<<<1024, 256, 0, stream>>>(XW, Gflat, P);
    reduce4<<<4096, 256, 0, stream>>>(P, out);
}

// Round 7
// 221.637 us; speedup vs baseline: 1.0283x; 1.0283x over previous
//
#include <hip/hip_runtime.h>
#include <math.h>

typedef __attribute__((ext_vector_type(8))) short short8;
typedef __attribute__((ext_vector_type(4))) float floatx4;

__device__ __forceinline__ void load_lds16(const void* g, void* l) {
    __builtin_amdgcn_global_load_lds((const __attribute__((address_space(1))) void*)g,
                                     (__attribute__((address_space(3))) void*)l,
                                     16, 0, 0);
}

__device__ __forceinline__ unsigned short f2bf(float x) {
    union { float f; unsigned int u; } v; v.f = x;
    unsigned int r = v.u + 0x7fffu + ((v.u >> 16) & 1u);
    return (unsigned short)(r >> 16);
}

// pack two fp32 -> two bf16 (round-half-up) in one v_perm_b32
__device__ __forceinline__ unsigned int pack_bf(float f0, float f1) {
    union { float f; unsigned int u; } a, b;
    a.f = f0; b.f = f1;
    return __builtin_amdgcn_perm(b.u + 0x8000u, a.u + 0x8000u, 0x07060302u);
}

__device__ __forceinline__ float fast_exp2(float x) {
#if __has_builtin(__builtin_amdgcn_exp2f)
    return __builtin_amdgcn_exp2f(x);
#else
    return __expf(x * 0.69314718056f);
#endif
}

__device__ __forceinline__ float fast_rcp(float x) {
#if __has_builtin(__builtin_amdgcn_rcpf)
    return __builtin_amdgcn_rcpf(x);
#else
    return 1.0f / x;
#endif
}

#define NEG_LOG2E (-1.4426950408889634f)

// ---- prep: weights -> bf16 in MFMA-fragment order + Toeplitz XW build ----
// blocks: [0,512) w0 | [512,6656) w | [6656,7680) wf-pad | [7680,11776) XW rows
__global__ void prep(const float* __restrict__ w0, const float* __restrict__ w,
                     const float* __restrict__ wf, const float* __restrict__ xi,
                     unsigned short* __restrict__ w0d, unsigned short* __restrict__ wd,
                     unsigned short* __restrict__ wfd, unsigned int* __restrict__ xw) {
    const int bid = blockIdx.x;
    if (bid < 6656) {
        const bool is0 = bid < 512;
        const int c = (is0 ? bid : bid - 512) * 256 + threadIdx.x;
        const int cpm = is0 ? 2048 : 8192;
        const int Kk  = is0 ? 2 : 8;
        const int K   = Kk * 32;
        const int mm  = c / cpm;
        const int cm  = c - mm * cpm;
        const int rblk = cm / (Kk * 64);
        const int rem  = cm - rblk * (Kk * 64);
        const int kk   = rem >> 6;
        const int lane = rem & 63;
        const int r  = rblk * 16 + (lane & 15);
        const int k0 = kk * 32 + (lane >> 4) * 8;
        const float* srcp = (is0 ? w0 : w) + ((size_t)mm * 256 + r) * K + k0;
        unsigned short* dstp = (is0 ? w0d : wd) + (size_t)c * 8;
        float4 a = *(const float4*)srcp;
        float4 b = *(const float4*)(srcp + 4);
        short8 o = { (short)f2bf(a.x), (short)f2bf(a.y), (short)f2bf(a.z), (short)f2bf(a.w),
                     (short)f2bf(b.x), (short)f2bf(b.y), (short)f2bf(b.z), (short)f2bf(b.w) };
        *(short8*)dstp = o;
    } else if (bid < 7680) {
        const int c = (bid - 6656) * 256 + threadIdx.x;
        const int m  = c >> 12;
        const int cm = c & 4095;
        const int rblk = cm >> 9;
        const int rem  = cm & 511;
        const int kk   = rem >> 6;
        const int lane = rem & 63;
        const int r  = rblk * 16 + (lane & 15);
        const int k0 = kk * 32 + (lane >> 4) * 8;
        short8 o = {0,0,0,0,0,0,0,0};
        if (r < 65) {
            const float* srcp = wf + ((size_t)m * 65 + r) * 256 + k0;
            float4 a = *(const float4*)srcp;
            float4 b = *(const float4*)(srcp + 4);
            o = (short8){ (short)f2bf(a.x), (short)f2bf(a.y), (short)f2bf(a.z), (short)f2bf(a.w),
                          (short)f2bf(b.x), (short)f2bf(b.y), (short)f2bf(b.z), (short)f2bf(b.w) };
        }
        *(short8*)(wfd + (size_t)c * 8) = o;
    } else {
        const int n = bid - 7680;
        #pragma unroll
        for (int t = 0; t < 9; ++t) {
            const int idx = t * 256 + threadIdx.x;
            if (idx < 2176) {
                const int m = idx / 34;
                const int pos = idx - m * 34;
                const int j0 = pos * 2;
                const float* xim = xi + (size_t)m * 4160 + n;
                const float v0 = (j0 < 65) ? xim[j0] : 0.0f;
                const float v1 = (j0 + 1 < 65) ? xim[j0 + 1] : 0.0f;
                xw[(size_t)n * 2176 + idx] =
                    (unsigned int)f2bf(v0) | ((unsigned int)f2bf(v1) << 16);
            }
        }
    }
}

// ---- weight fragments -> registers, once per layer ----
template<int K, int I>
__device__ __forceinline__ void load_w(
    const unsigned short* __restrict__ Wt, int wave, int lane, short8 (&w)[I][K / 32])
{
    constexpr int Kk = K / 32;
    const unsigned short* wb = Wt + ((size_t)(wave * I * Kk) * 64 + lane) * 8;
    #pragma unroll
    for (int i = 0; i < I; ++i)
        #pragma unroll
        for (int kk = 0; kk < Kk; ++kk)
            w[i][kk] = *(const short8*)(wb + (size_t)(i * Kk + kk) * 512);
}

// ---- MFMA sweep over one 32-batch col-group q (J=2), weights from registers ----
// X layout: X[b][k] at b*K + ((k/8) ^ (b&7))*8 + (k&7)   (shorts)
template<int K>
__device__ __forceinline__ void mfma_q(
    const short8 (&w)[4][K / 32], const unsigned short* src, int q,
    int quad, int l16, floatx4 (&acc)[4][2])
{
    constexpr int Kk = K / 32;
    #pragma unroll
    for (int i = 0; i < 4; ++i)
        #pragma unroll
        for (int j = 0; j < 2; ++j) acc[i][j] = (floatx4){0.f, 0.f, 0.f, 0.f};
    #pragma unroll
    for (int kk = 0; kk < Kk; ++kk) {
        short8 bf[2];
        #pragma unroll
        for (int j = 0; j < 2; ++j) {
            const int cb = q * 32 + j * 16 + l16;
            bf[j] = *(const short8*)&src[cb * K + (((kk * 4 + quad) ^ (cb & 7)) * 8)];
        }
        #pragma unroll
        for (int i = 0; i < 4; ++i)
            #pragma unroll
            for (int j = 0; j < 2; ++j)
                acc[i][j] = __builtin_amdgcn_mfma_f32_16x16x32_bf16(w[i][kk], bf[j], acc[i][j], 0, 0, 0);
    }
}

// epilogue for col-group q: fused bias+sigmoid, perm pack, K_out=256 layout
__device__ __forceinline__ void write_q(
    const float* __restrict__ bm, unsigned short* dst, int q,
    int wave, int quad, int l16, floatx4 (&acc)[4][2])
{
    const int rbw = wave * 64;
    #pragma unroll
    for (int i = 0; i < 4; ++i) {
        const int rb = rbw + i * 16 + quad * 4;
        float c0 = bm[rb]     * NEG_LOG2E;
        float c1 = bm[rb + 1] * NEG_LOG2E;
        float c2 = bm[rb + 2] * NEG_LOG2E;
        float c3 = bm[rb + 3] * NEG_LOG2E;
        #pragma unroll
        for (int j = 0; j < 2; ++j) {
            const int cb = q * 32 + j * 16 + l16;
            float r0 = fast_rcp(1.0f + fast_exp2(fmaf(acc[i][j][0], NEG_LOG2E, c0)));
            float r1 = fast_rcp(1.0f + fast_exp2(fmaf(acc[i][j][1], NEG_LOG2E, c1)));
            float r2 = fast_rcp(1.0f + fast_exp2(fmaf(acc[i][j][2], NEG_LOG2E, c2)));
            float r3 = fast_rcp(1.0f + fast_exp2(fmaf(acc[i][j][3], NEG_LOG2E, c3)));
            uint2 o = { pack_bf(r0, r1), pack_bf(r2, r3) };
            *(uint2*)&dst[cb * 256 + (((rb >> 3) ^ (cb & 7)) * 8) + (rb & 7)] = o;
        }
    }
}

// ---- final-layer J=4 sweep (R5-proven) ----
template<int K, int I>
__device__ __forceinline__ void mfma_tile(
    const short8 (&w)[I][K / 32], const unsigned short* src, int t,
    int quad, int l16, floatx4 (&acc)[I][4])
{
    constexpr int Kk = K / 32;
    #pragma unroll
    for (int i = 0; i < I; ++i)
        #pragma unroll
        for (int j = 0; j < 4; ++j) acc[i][j] = (floatx4){0.f, 0.f, 0.f, 0.f};
    #pragma unroll
    for (int kk = 0; kk < Kk; ++kk) {
        short8 bf[4];
        #pragma unroll
        for (int j = 0; j < 4; ++j) {
            const int cb = t * 64 + j * 16 + l16;
            bf[j] = *(const short8*)&src[cb * K + (((kk * 4 + quad) ^ (cb & 7)) * 8)];
        }
        #pragma unroll
        for (int i = 0; i < I; ++i)
            #pragma unroll
            for (int j = 0; j < 4; ++j)
                acc[i][j] = __builtin_amdgcn_mfma_f32_16x16x32_bf16(w[i][kk], bf[j], acc[i][j], 0, 0, 0);
    }
}

// ---- fused MLP, weight-register-resident + ping-pong sweep pipeline (R7) ----
// grid 512 = 64 m x 8 batch-tiles of 128; 256 thr (4 waves, I=4); 2 blocks/CU.
// R6 lesson: LDS reads/MFMA = 1/I -> I=4 is the feasible minimum; R5's loss was
// the acc WAR chain serializing write(q) against mfma(q+1). Fix: 4 col-sweeps
// of 32 (J=2) with ping-pong accA/accB: window { mfma(q+1)->B || write(q)<-A },
// one barrier per window. b-ranges are disjoint across window ops (write q-1
// vs read q), so races are impossible; weight loads for the next layer issue
// 3-4 windows early. Layer0 reads a separate Xin buffer (80 KB LDS total,
// 2 blocks = exactly 160 KB) -> no in-place hazard, barrier-free ping-pong.
__global__ __launch_bounds__(256, 2)
void fused_mlp(const float* __restrict__ u,
               const unsigned short* __restrict__ w0_bf, const float* __restrict__ b0_,
               const unsigned short* __restrict__ w_bf,  const float* __restrict__ b_,
               const unsigned short* __restrict__ wf_bf, const float* __restrict__ bf_,
               unsigned short* __restrict__ Gflat) {
    __shared__ unsigned short X[128 * 256];    // 64 KB  (activations, K_out=256)
    __shared__ unsigned short Xin[128 * 64];   // 16 KB  (layer-0 input, K=64)

    const int bid = blockIdx.x;
    const int xcd = bid & 7, slot = bid >> 3;           // slot 0..63
    const int m  = (xcd << 3) + (slot >> 3);            // 8 m per XCD
    const int b0 = (slot & 7) << 7;                     // 8 batch-tiles of 128
    const int tid = threadIdx.x, wave = tid >> 6, lane = tid & 63;
    const int quad = lane >> 4, l16 = lane & 15;

    // stage u (fp32) -> Xin (bf16, K=64 layout), perm-packed
    {
        const int b = tid >> 1, hk = tid & 1;
        const float* up = u + (size_t)(b0 + b) * 64 + hk * 32;
        #pragma unroll
        for (int c = 0; c < 4; ++c) {
            float4 v0 = *(const float4*)(up + c * 8);
            float4 v1 = *(const float4*)(up + c * 8 + 4);
            uint4 p = { pack_bf(v0.x, v0.y), pack_bf(v0.z, v0.w),
                        pack_bf(v1.x, v1.y), pack_bf(v1.z, v1.w) };
            *(uint4*)&Xin[b * 64 + (((hk * 4 + c) ^ (b & 7)) * 8)] = p;
        }
    }
    __syncthreads();

    floatx4 aA[4][2], aB[4][2];
    short8 wr[4][8];

    // ---- layer 0 (K=64, Xin -> X, no barriers needed: disjoint buffers;
    //      main-layer weight load issued mid-stream, hidden under epilogues) ----
    {
        short8 w0r[4][2];
        load_w<64, 4>(w0_bf + (size_t)m * 16384, wave, lane, w0r);
        const float* bm = b0_ + (size_t)m * 256;
        mfma_q<64>(w0r, Xin, 0, quad, l16, aA);
        mfma_q<64>(w0r, Xin, 1, quad, l16, aB); write_q(bm, X, 0, wave, quad, l16, aA);
        mfma_q<64>(w0r, Xin, 2, quad, l16, aA); write_q(bm, X, 1, wave, quad, l16, aB);
        load_w<256, 4>(w_bf + (size_t)m * 65536, wave, lane, wr);   // l=0 weights, ~800cy cover
        mfma_q<64>(w0r, Xin, 3, quad, l16, aB); write_q(bm, X, 2, wave, quad, l16, aA);
        write_q(bm, X, 3, wave, quad, l16, aB);
    }
    __syncthreads();

    const float* bm0 = b_ + (size_t)m * 256;
    const float* bm1 = b_ + ((size_t)64 + m) * 256;
    const float* bm2 = b_ + ((size_t)128 + m) * 256;

    // ---- main pipeline: window = { mfma(q+1) || write(q) }, 1 barrier each ----
    mfma_q<256>(wr, X, 0, quad, l16, aA);
    __syncthreads();
    // layer 0 (main) core
    mfma_q<256>(wr, X, 1, quad, l16, aB); write_q(bm0, X, 0, wave, quad, l16, aA);
    __syncthreads();
    mfma_q<256>(wr, X, 2, quad, l16, aA); write_q(bm0, X, 1, wave, quad, l16, aB);
    __syncthreads();
    mfma_q<256>(wr, X, 3, quad, l16, aB); write_q(bm0, X, 2, wave, quad, l16, aA);
    __syncthreads();
    // boundary: load l=1 weights; W3(l0) || M0(l1)  (b-ranges 3 vs 0: disjoint)
    load_w<256, 4>(w_bf + ((size_t)64 + m) * 65536, wave, lane, wr);
    write_q(bm0, X, 3, wave, quad, l16, aB);
    mfma_q<256>(wr, X, 0, quad, l16, aA);
    __syncthreads();
    // layer 1 core
    mfma_q<256>(wr, X, 1, quad, l16, aB); write_q(bm1, X, 0, wave, quad, l16, aA);
    __syncthreads();
    mfma_q<256>(wr, X, 2, quad, l16, aA); write_q(bm1, X, 1, wave, quad, l16, aB);
    __syncthreads();
    mfma_q<256>(wr, X, 3, quad, l16, aB); write_q(bm1, X, 2, wave, quad, l16, aA);
    __syncthreads();
    // boundary: load l=2 weights; W3(l1) || M0(l2)
    load_w<256, 4>(w_bf + ((size_t)128 + m) * 65536, wave, lane, wr);
    write_q(bm1, X, 3, wave, quad, l16, aB);
    mfma_q<256>(wr, X, 0, quad, l16, aA);
    __syncthreads();
    // layer 2 core
    mfma_q<256>(wr, X, 1, quad, l16, aB); write_q(bm2, X, 0, wave, quad, l16, aA);
    __syncthreads();
    mfma_q<256>(wr, X, 2, quad, l16, aA); write_q(bm2, X, 1, wave, quad, l16, aB);
    __syncthreads();
    mfma_q<256>(wr, X, 3, quad, l16, aB); write_q(bm2, X, 2, wave, quad, l16, aA);
    __syncthreads();
    // tail: load final weights; W3(l2)
    short8 wfr[2][8];
    load_w<256, 2>(wf_bf + (size_t)m * 32768, wave, lane, wfr);
    write_q(bm2, X, 3, wave, quad, l16, aB);
    __syncthreads();

    // ---- final layer (K=256, 68 padded rows): direct global G write ----
    {
        const float* bm = bf_ + (size_t)m * 65;
        unsigned short* Gg = Gflat + (size_t)b0 * 4352 + m * 68;
        floatx4 acf[2][4];
        #pragma unroll
        for (int t = 0; t < 2; ++t) {
            mfma_tile<256, 2>(wfr, X, t, quad, l16, acf);
            #pragma unroll
            for (int i = 0; i < 2; ++i) {
                const int rb = wave * 32 + i * 16 + quad * 4;
                if (rb < 68) {
                    float c[4];
                    #pragma unroll
                    for (int rr = 0; rr < 4; ++rr)
                        c[rr] = (rb + rr < 65) ? bm[rb + rr] * NEG_LOG2E : 0.0f;
                    #pragma unroll
                    for (int j = 0; j < 4; ++j) {
                        const int cb = t * 64 + j * 16 + l16;
                        float r0 = fast_rcp(1.0f + fast_exp2(fmaf(acf[i][j][0], NEG_LOG2E, c[0])));
                        float r1 = fast_rcp(1.0f + fast_exp2(fmaf(acf[i][j][1], NEG_LOG2E, c[1])));
                        float r2 = fast_rcp(1.0f + fast_exp2(fmaf(acf[i][j][2], NEG_LOG2E, c[2])));
                        float r3 = fast_rcp(1.0f + fast_exp2(fmaf(acf[i][j][3], NEG_LOG2E, c[3])));
                        uint2 o = { pack_bf(r0, r1), pack_bf(r2, r3) };
                        *(uint2*)&Gg[(size_t)cb * 4352 + rb] = o;
                    }
                }
            }
        }
    }
}

// ---- contraction: P[kc][n][b] partials; K=4352, K-split x2, 256 thr, 128x128 ----
// K-split 4->2 halves the P round-trip (R6 analysis: P+reduce was ~144 MB HBM,
// now ~80 MB). grid 512 = 2 blocks/CU.
__global__ __launch_bounds__(256, 3)
void contract_gemm(const unsigned short* __restrict__ XW,
                   const unsigned short* __restrict__ G,
                   float* __restrict__ P) {
    const int bid = blockIdx.x;
    const int xcd = bid & 7, slot = bid >> 3;          // 0..63
    const int kc  = slot >> 5;                          // 0..1
    const int rst = slot & 31;
    const int r0 = ((xcd << 2) + (rst >> 3)) << 7;      // n-tile (XCD-colocated)
    const int c0 = (rst & 7) << 7;                      // b-tile
    const int kb = kc * 2176;
    float* Pc = P + (size_t)kc * 4096 * 1024;

    __shared__ unsigned short As[128 * 64];
    __shared__ unsigned short Bs[128 * 64];

    const int tid = threadIdx.x;
    const int wave = tid >> 6, lane = tid & 63;
    const int quad = lane >> 4, l16 = lane & 15;
    const int wr = (wave & 1) * 64;
    const int wc = (wave >> 1) * 64;
    const int srow = wave * 32 + (lane >> 3);
    const int spos = lane & 7;

    floatx4 acc[4][4];
    const floatx4 zero = {0.f, 0.f, 0.f, 0.f};
    #pragma unroll
    for (int i = 0; i < 4; ++i)
        #pragma unroll
        for (int j = 0; j < 4; ++j) acc[i][j] = zero;

    for (int k0 = kb; k0 < kb + 2176; k0 += 64) {
        #pragma unroll
        for (int t = 0; t < 4; ++t) {
            const int row = srow + t * 8;
            const int fc  = spos ^ (row & 7);
            load_lds16(XW + (size_t)(r0 + row) * 4352 + k0 + fc * 8,
                       &As[(wave * 32 + t * 8) * 64]);
            load_lds16(G + (size_t)(c0 + row) * 4352 + k0 + fc * 8,
                       &Bs[(wave * 32 + t * 8) * 64]);
        }
        __syncthreads();

        #pragma unroll
        for (int kk = 0; kk < 2; ++kk) {
            short8 af[4], bfr[4];
            #pragma unroll
            for (int i = 0; i < 4; ++i) {
                const int ra = wr + i * 16 + l16;
                af[i]  = *(const short8*)&As[ra * 64 + (((kk * 4 + quad) ^ (ra & 7)) * 8)];
                const int cb = wc + i * 16 + l16;
                bfr[i] = *(const short8*)&Bs[cb * 64 + (((kk * 4 + quad) ^ (cb & 7)) * 8)];
            }
            #pragma unroll
            for (int i = 0; i < 4; ++i)
                #pragma unroll
                for (int j = 0; j < 4; ++j)
                    acc[i][j] = __builtin_amdgcn_mfma_f32_16x16x32_bf16(af[i], bfr[j], acc[i][j], 0, 0, 0);
        }
        __syncthreads();
    }

    #pragma unroll
    for (int i = 0; i < 4; ++i) {
        const int rb = r0 + wr + i * 16 + quad * 4;
        #pragma unroll
        for (int rr = 0; rr < 4; ++rr)
            #pragma unroll
            for (int j = 0; j < 4; ++j) {
                const int col = c0 + wc + j * 16 + l16;
                Pc[(size_t)(rb + rr) * 1024 + col] = acc[i][j][rr];
            }
    }
}

// ---- final reduce of 2 K-partials ----
__global__ void reduce2(const float* __restrict__ P, float* __restrict__ out) {
    const int i = blockIdx.x * 256 + threadIdx.x;
    const float4* p = (const float4*)P;
    float4 a = p[i], b = p[i + 1048576];
    ((float4*)out)[i] = (float4){ a.x + b.x, a.y + b.y, a.z + b.z, a.w + b.w };
}

extern "C" void kernel_launch(void* const* d_in, const int* in_sizes, int n_in,
                              void* d_out, int out_size, void* d_ws, size_t ws_size,
                              hipStream_t stream) {
    const float* u   = (const float*)d_in[0];
    const float* w0  = (const float*)d_in[1];
    const float* b0_ = (const float*)d_in[2];
    const float* w   = (const float*)d_in[3];
    const float* b   = (const float*)d_in[4];
    const float* wf  = (const float*)d_in[5];
    const float* bf_ = (const float*)d_in[6];
    const float* xi  = (const float*)d_in[7];
    float* out = (float*)d_out;

    unsigned short* w0_bf = (unsigned short*)d_ws;             // 1,048,576
    unsigned short* w_bf  = w0_bf + 1048576;                   // 12,582,912
    unsigned short* wf_bf = w_bf  + 12582912;                  // 2,097,152
    unsigned short* Gflat = wf_bf + 2097152;                   // 4,456,448 (1024 x 4352)
    unsigned short* XW    = Gflat + 4456448;                   // 17,825,792 (4096 x 4352)
    float*          P     = (float*)(XW + 17825792);           // 2 x 4096 x 1024 fp32

    prep<<<11776, 256, 0, stream>>>(w0, w, wf, xi, w0_bf, w_bf, wf_bf, (unsigned int*)XW);
    fused_mlp<<<512, 256, 0, stream>>>(u, w0_bf, b0_, w_bf, b, wf_bf, bf_, Gflat);
    contract_gemm<<<512, 256, 0, stream>>>(XW, Gflat, P);
    reduce2<<<4096, 256, 0, stream>>>(P, out);
}

// Round 9
// 218.949 us; speedup vs baseline: 1.0409x; 1.0123x over previous
//
#include <hip/hip_runtime.h>
#include <math.h>

typedef __attribute__((ext_vector_type(8))) short short8;
typedef __attribute__((ext_vector_type(4))) float floatx4;

__device__ __forceinline__ void load_lds16(const void* g, void* l) {
    __builtin_amdgcn_global_load_lds((const __attribute__((address_space(1))) void*)g,
                                     (__attribute__((address_space(3))) void*)l,
                                     16, 0, 0);
}

__device__ __forceinline__ unsigned short f2bf(float x) {
    union { float f; unsigned int u; } v; v.f = x;
    unsigned int r = v.u + 0x7fffu + ((v.u >> 16) & 1u);
    return (unsigned short)(r >> 16);
}

// pack two fp32 -> two bf16 (round-half-up) in one v_perm_b32
__device__ __forceinline__ unsigned int pack_bf(float f0, float f1) {
    union { float f; unsigned int u; } a, b;
    a.f = f0; b.f = f1;
    return __builtin_amdgcn_perm(b.u + 0x8000u, a.u + 0x8000u, 0x07060302u);
}

__device__ __forceinline__ float fast_exp2(float x) {
#if __has_builtin(__builtin_amdgcn_exp2f)
    return __builtin_amdgcn_exp2f(x);
#else
    return __expf(x * 0.69314718056f);
#endif
}

__device__ __forceinline__ float fast_rcp(float x) {
#if __has_builtin(__builtin_amdgcn_rcpf)
    return __builtin_amdgcn_rcpf(x);
#else
    return 1.0f / x;
#endif
}

#define NEG_LOG2E (-1.4426950408889634f)

// ---- prep: weights -> bf16 in MFMA-fragment order + Toeplitz XW build ----
// blocks: [0,512) w0 | [512,6656) w | [6656,7680) wf-pad | [7680,11776) XW rows
__global__ void prep(const float* __restrict__ w0, const float* __restrict__ w,
                     const float* __restrict__ wf, const float* __restrict__ xi,
                     unsigned short* __restrict__ w0d, unsigned short* __restrict__ wd,
                     unsigned short* __restrict__ wfd, unsigned int* __restrict__ xw) {
    const int bid = blockIdx.x;
    if (bid < 6656) {
        const bool is0 = bid < 512;
        const int c = (is0 ? bid : bid - 512) * 256 + threadIdx.x;
        const int cpm = is0 ? 2048 : 8192;
        const int Kk  = is0 ? 2 : 8;
        const int K   = Kk * 32;
        const int mm  = c / cpm;
        const int cm  = c - mm * cpm;
        const int rblk = cm / (Kk * 64);
        const int rem  = cm - rblk * (Kk * 64);
        const int kk   = rem >> 6;
        const int lane = rem & 63;
        const int r  = rblk * 16 + (lane & 15);
        const int k0 = kk * 32 + (lane >> 4) * 8;
        const float* srcp = (is0 ? w0 : w) + ((size_t)mm * 256 + r) * K + k0;
        unsigned short* dstp = (is0 ? w0d : wd) + (size_t)c * 8;
        float4 a = *(const float4*)srcp;
        float4 b = *(const float4*)(srcp + 4);
        short8 o = { (short)f2bf(a.x), (short)f2bf(a.y), (short)f2bf(a.z), (short)f2bf(a.w),
                     (short)f2bf(b.x), (short)f2bf(b.y), (short)f2bf(b.z), (short)f2bf(b.w) };
        *(short8*)dstp = o;
    } else if (bid < 7680) {
        const int c = (bid - 6656) * 256 + threadIdx.x;
        const int m  = c >> 12;
        const int cm = c & 4095;
        const int rblk = cm >> 9;
        const int rem  = cm & 511;
        const int kk   = rem >> 6;
        const int lane = rem & 63;
        const int r  = rblk * 16 + (lane & 15);
        const int k0 = kk * 32 + (lane >> 4) * 8;
        short8 o = {0,0,0,0,0,0,0,0};
        if (r < 65) {
            const float* srcp = wf + ((size_t)m * 65 + r) * 256 + k0;
            float4 a = *(const float4*)srcp;
            float4 b = *(const float4*)(srcp + 4);
            o = (short8){ (short)f2bf(a.x), (short)f2bf(a.y), (short)f2bf(a.z), (short)f2bf(a.w),
                          (short)f2bf(b.x), (short)f2bf(b.y), (short)f2bf(b.z), (short)f2bf(b.w) };
        }
        *(short8*)(wfd + (size_t)c * 8) = o;
    } else {
        const int n = bid - 7680;
        #pragma unroll
        for (int t = 0; t < 9; ++t) {
            const int idx = t * 256 + threadIdx.x;
            if (idx < 2176) {
                const int m = idx / 34;
                const int pos = idx - m * 34;
                const int j0 = pos * 2;
                const float* xim = xi + (size_t)m * 4160 + n;
                const float v0 = (j0 < 65) ? xim[j0] : 0.0f;
                const float v1 = (j0 + 1 < 65) ? xim[j0 + 1] : 0.0f;
                xw[(size_t)n * 2176 + idx] =
                    (unsigned int)f2bf(v0) | ((unsigned int)f2bf(v1) << 16);
            }
        }
    }
}

// ---- weight fragments -> registers, once per layer (amortized over 2 sub-tiles) ----
template<int K, int I>
__device__ __forceinline__ void load_w(
    const unsigned short* __restrict__ Wt, int wave, int lane, short8 (&w)[I][K / 32])
{
    constexpr int Kk = K / 32;
    const unsigned short* wb = Wt + ((size_t)(wave * I * Kk) * 64 + lane) * 8;
    #pragma unroll
    for (int i = 0; i < I; ++i)
        #pragma unroll
        for (int kk = 0; kk < Kk; ++kk)
            w[i][kk] = *(const short8*)(wb + (size_t)(i * Kk + kk) * 512);
}

// ---- MFMA sweep over one 64-col sub-tile t, weights from registers ----
// X layout: X[b][k] at b*K + ((k/8) ^ (b&7))*8 + (k&7)   (shorts)
template<int K, int I>
__device__ __forceinline__ void mfma_tile(
    const short8 (&w)[I][K / 32], const unsigned short* src, int t,
    int quad, int l16, floatx4 (&acc)[I][4])
{
    constexpr int Kk = K / 32;
    #pragma unroll
    for (int i = 0; i < I; ++i)
        #pragma unroll
        for (int j = 0; j < 4; ++j) acc[i][j] = (floatx4){0.f, 0.f, 0.f, 0.f};
    #pragma unroll
    for (int kk = 0; kk < Kk; ++kk) {
        short8 bf[4];
        #pragma unroll
        for (int j = 0; j < 4; ++j) {
            const int cb = t * 64 + j * 16 + l16;
            bf[j] = *(const short8*)&src[cb * K + (((kk * 4 + quad) ^ (cb & 7)) * 8)];
        }
        #pragma unroll
        for (int i = 0; i < I; ++i)
            #pragma unroll
            for (int j = 0; j < 4; ++j)
                acc[i][j] = __builtin_amdgcn_mfma_f32_16x16x32_bf16(w[i][kk], bf[j], acc[i][j], 0, 0, 0);
    }
}

// epilogue for sub-tile t: fused bias+sigmoid, perm pack, in-place K_out=256 layout
template<int I>
__device__ __forceinline__ void mlp_write_t(
    const float* __restrict__ bm, unsigned short* dst, int t,
    int wave, int quad, int l16, floatx4 (&acc)[I][4])
{
    const int rbw = wave * (I * 16);
    #pragma unroll
    for (int i = 0; i < I; ++i) {
        const int rb = rbw + i * 16 + quad * 4;
        float c0 = bm[rb]     * NEG_LOG2E;
        float c1 = bm[rb + 1] * NEG_LOG2E;
        float c2 = bm[rb + 2] * NEG_LOG2E;
        float c3 = bm[rb + 3] * NEG_LOG2E;
        #pragma unroll
        for (int j = 0; j < 4; ++j) {
            const int cb = t * 64 + j * 16 + l16;
            float r0 = fast_rcp(1.0f + fast_exp2(fmaf(acc[i][j][0], NEG_LOG2E, c0)));
            float r1 = fast_rcp(1.0f + fast_exp2(fmaf(acc[i][j][1], NEG_LOG2E, c1)));
            float r2 = fast_rcp(1.0f + fast_exp2(fmaf(acc[i][j][2], NEG_LOG2E, c2)));
            float r3 = fast_rcp(1.0f + fast_exp2(fmaf(acc[i][j][3], NEG_LOG2E, c3)));
            uint2 o = { pack_bf(r0, r1), pack_bf(r2, r3) };
            *(uint2*)&dst[cb * 256 + (((rb >> 3) ^ (cb & 7)) * 8) + (rb & 7)] = o;
        }
    }
}

// ---- fused MLP, weight-register-resident (R5 version — best measured, 49.8 us) ----
// grid 512 = 64 m x 8 batch-tiles of 128; 256 thr; 2 blocks/CU (64 KB LDS each).
// Per layer each wave loads its 64 weight rows ONCE into 128 VGPRs and sweeps
// 2 sub-tiles (MFMA:weight-load 8:1). R6/R7 variants (8-wave, ping-pong) both
// landed 51-55 -> this is the structural floor for this schedule family.
__global__ __launch_bounds__(256, 2)
void fused_mlp(const float* __restrict__ u,
               const unsigned short* __restrict__ w0_bf, const float* __restrict__ b0_,
               const unsigned short* __restrict__ w_bf,  const float* __restrict__ b_,
               const unsigned short* __restrict__ wf_bf, const float* __restrict__ bf_,
               unsigned short* __restrict__ Gflat) {
    __shared__ unsigned short X[128 * 256];   // 64 KB

    const int bid = blockIdx.x;
    const int xcd = bid & 7, slot = bid >> 3;           // slot 0..63
    const int m  = (xcd << 3) + (slot >> 3);            // 8 m per XCD
    const int b0 = (slot & 7) << 7;                     // 8 batch-tiles of 128
    const int tid = threadIdx.x, wave = tid >> 6, lane = tid & 63;
    const int quad = lane >> 4, l16 = lane & 15;

    // stage u (fp32) -> X (bf16, K=64 layout), perm-packed
    {
        const int b = tid >> 1, hk = tid & 1;
        const float* up = u + (size_t)(b0 + b) * 64 + hk * 32;
        #pragma unroll
        for (int c = 0; c < 4; ++c) {
            float4 v0 = *(const float4*)(up + c * 8);
            float4 v1 = *(const float4*)(up + c * 8 + 4);
            uint4 p = { pack_bf(v0.x, v0.y), pack_bf(v0.z, v0.w),
                        pack_bf(v1.x, v1.y), pack_bf(v1.z, v1.w) };
            *(uint4*)&X[b * 64 + (((hk * 4 + c) ^ (b & 7)) * 8)] = p;
        }
    }
    __syncthreads();

    floatx4 acc[4][4];

    // ---- layer 0 (K=64): both sub-tiles computed before any write ----
    {
        short8 w0r[4][2];
        load_w<64, 4>(w0_bf + (size_t)m * 16384, wave, lane, w0r);
        floatx4 acc2[4][4];
        mfma_tile<64, 4>(w0r, X, 0, quad, l16, acc);
        mfma_tile<64, 4>(w0r, X, 1, quad, l16, acc2);
        __syncthreads();
        mlp_write_t<4>(b0_ + (size_t)m * 256, X, 0, wave, quad, l16, acc);
        mlp_write_t<4>(b0_ + (size_t)m * 256, X, 1, wave, quad, l16, acc2);
        __syncthreads();
    }

    // ---- main layers (K=256): weights in regs, 2 sub-tiles, 2 barriers/layer ----
    #pragma unroll 1
    for (int l = 0; l < 3; ++l) {
        short8 wr[4][8];
        load_w<256, 4>(w_bf + ((size_t)l * 64 + m) * 65536, wave, lane, wr);
        const float* bm = b_ + ((size_t)l * 64 + m) * 256;
        mfma_tile<256, 4>(wr, X, 0, quad, l16, acc);
        __syncthreads();
        mlp_write_t<4>(bm, X, 0, wave, quad, l16, acc);
        mfma_tile<256, 4>(wr, X, 1, quad, l16, acc);
        __syncthreads();
        mlp_write_t<4>(bm, X, 1, wave, quad, l16, acc);
    }
    __syncthreads();   // all w(1) writes visible before final layer reads tile 1

    // ---- final layer (K=256, 68 padded rows): direct global G write ----
    {
        short8 wfr[2][8];
        load_w<256, 2>(wf_bf + (size_t)m * 32768, wave, lane, wfr);
        const float* bm = bf_ + (size_t)m * 65;
        unsigned short* Gg = Gflat + (size_t)b0 * 4352 + m * 68;
        floatx4 acf[2][4];
        #pragma unroll
        for (int t = 0; t < 2; ++t) {
            mfma_tile<256, 2>(wfr, X, t, quad, l16, acf);
            #pragma unroll
            for (int i = 0; i < 2; ++i) {
                const int rb = wave * 32 + i * 16 + quad * 4;
                if (rb < 68) {
                    float c[4];
                    #pragma unroll
                    for (int rr = 0; rr < 4; ++rr)
                        c[rr] = (rb + rr < 65) ? bm[rb + rr] * NEG_LOG2E : 0.0f;
                    #pragma unroll
                    for (int j = 0; j < 4; ++j) {
                        const int cb = t * 64 + j * 16 + l16;
                        float r0 = fast_rcp(1.0f + fast_exp2(fmaf(acf[i][j][0], NEG_LOG2E, c[0])));
                        float r1 = fast_rcp(1.0f + fast_exp2(fmaf(acf[i][j][1], NEG_LOG2E, c[1])));
                        float r2 = fast_rcp(1.0f + fast_exp2(fmaf(acf[i][j][2], NEG_LOG2E, c[2])));
                        float r3 = fast_rcp(1.0f + fast_exp2(fmaf(acf[i][j][3], NEG_LOG2E, c[3])));
                        uint2 o = { pack_bf(r0, r1), pack_bf(r2, r3) };
                        *(uint2*)&Gg[(size_t)cb * 4352 + rb] = o;
                    }
                }
            }
        }
    }
}

// ---- contraction: FULL-K (no P partials, no reduce kernel), 128n x 64b tiles ----
// grid 512 = 32 n-tiles x 16 b-tiles, 2 blocks/CU, 68 K-iters, fp32 direct to out.
// R8: removes the P round-trip (67 MB HBM) and the reduce2 dispatch entirely;
// cost is af[4]+bf[2] per 8 MFMAs (+50% LDS/stage per MFMA) — absorbed by
// cross-block slack at 2 blocks/CU. XCD-swizzle keeps 4 n-tiles (XW slice
// ~4.5 MB) resident per XCD L2.
__global__ __launch_bounds__(256, 2)
void contract_gemm(const unsigned short* __restrict__ XW,
                   const unsigned short* __restrict__ G,
                   float* __restrict__ out) {
    const int bid = blockIdx.x;
    const int xcd = bid & 7, slot = bid >> 3;           // 0..63
    const int r0 = ((xcd << 2) + (slot >> 4)) << 7;     // n-tile 0..31 (XCD-colocated)
    const int c0 = (slot & 15) << 6;                    // b-tile 0..15 (64 cols)

    __shared__ unsigned short As[128 * 64];             // 16 KB
    __shared__ unsigned short Bs[64 * 64];              // 8 KB

    const int tid = threadIdx.x;
    const int wave = tid >> 6, lane = tid & 63;
    const int quad = lane >> 4, l16 = lane & 15;
    const int wr = (wave & 1) * 64;                     // wave n-offset
    const int wc = (wave >> 1) * 32;                    // wave b-offset
    const int lrow = lane >> 3;
    const int spos = lane & 7;

    floatx4 acc[4][2];
    #pragma unroll
    for (int i = 0; i < 4; ++i)
        #pragma unroll
        for (int j = 0; j < 2; ++j) acc[i][j] = (floatx4){0.f, 0.f, 0.f, 0.f};

    for (int k0 = 0; k0 < 4352; k0 += 64) {
        #pragma unroll
        for (int t = 0; t < 4; ++t) {
            const int row = wave * 32 + t * 8 + lrow;
            const int fc  = spos ^ (row & 7);
            load_lds16(XW + (size_t)(r0 + row) * 4352 + k0 + fc * 8,
                       &As[(wave * 32 + t * 8) * 64]);
        }
        #pragma unroll
        for (int t = 0; t < 2; ++t) {
            const int row = wave * 16 + t * 8 + lrow;
            const int fc  = spos ^ (row & 7);
            load_lds16(G + (size_t)(c0 + row) * 4352 + k0 + fc * 8,
                       &Bs[(wave * 16 + t * 8) * 64]);
        }
        __syncthreads();

        #pragma unroll
        for (int kk = 0; kk < 2; ++kk) {
            short8 af[4], bfr[2];
            #pragma unroll
            for (int i = 0; i < 4; ++i) {
                const int ra = wr + i * 16 + l16;
                af[i]  = *(const short8*)&As[ra * 64 + (((kk * 4 + quad) ^ (ra & 7)) * 8)];
            }
            #pragma unroll
            for (int j = 0; j < 2; ++j) {
                const int cb = wc + j * 16 + l16;
                bfr[j] = *(const short8*)&Bs[cb * 64 + (((kk * 4 + quad) ^ (cb & 7)) * 8)];
            }
            #pragma unroll
            for (int i = 0; i < 4; ++i)
                #pragma unroll
                for (int j = 0; j < 2; ++j)
                    acc[i][j] = __builtin_amdgcn_mfma_f32_16x16x32_bf16(af[i], bfr[j], acc[i][j], 0, 0, 0);
        }
        __syncthreads();
    }

    #pragma unroll
    for (int i = 0; i < 4; ++i) {
        const int rb = r0 + wr + i * 16 + quad * 4;
        #pragma unroll
        for (int rr = 0; rr < 4; ++rr)
            #pragma unroll
            for (int j = 0; j < 2; ++j) {
                const int col = c0 + wc + j * 16 + l16;
                out[(size_t)(rb + rr) * 1024 + col] = acc[i][j][rr];
            }
    }
}

extern "C" void kernel_launch(void* const* d_in, const int* in_sizes, int n_in,
                              void* d_out, int out_size, void* d_ws, size_t ws_size,
                              hipStream_t stream) {
    const float* u   = (const float*)d_in[0];
    const float* w0  = (const float*)d_in[1];
    const float* b0_ = (const float*)d_in[2];
    const float* w   = (const float*)d_in[3];
    const float* b   = (const float*)d_in[4];
    const float* wf  = (const float*)d_in[5];
    const float* bf_ = (const float*)d_in[6];
    const float* xi  = (const float*)d_in[7];
    float* out = (float*)d_out;

    unsigned short* w0_bf = (unsigned short*)d_ws;             // 1,048,576
    unsigned short* w_bf  = w0_bf + 1048576;                   // 12,582,912
    unsigned short* wf_bf = w_bf  + 12582912;                  // 2,097,152
    unsigned short* Gflat = wf_bf + 2097152;                   // 4,456,448 (1024 x 4352)
    unsigned short* XW    = Gflat + 4456448;                   // 17,825,792 (4096 x 4352)

    prep<<<11776, 256, 0, stream>>>(w0, w, wf, xi, w0_bf, w_bf, wf_bf, (unsigned int*)XW);
    fused_mlp<<<512, 256, 0, stream>>>(u, w0_bf, b0_, w_bf, b, wf_bf, bf_, Gflat);
    contract_gemm<<<512, 256, 0, stream>>>(XW, Gflat, out);
}